// Round 3
// baseline (748.294 us; speedup 1.0000x reference)
//
#include <hip/hip_runtime.h>
#include <hip/hip_bf16.h>

// ---------------- problem constants ----------------
#define T_TOK 2048
#define DMODEL 1024
#define DMLP 4096
#define NEXP 8
#define TOTROW (2 * T_TOK)  // total routed rows, always 4096
#define YB 4                // live m-tile blocks per expert

typedef __bf16 bf16x8 __attribute__((ext_vector_type(8)));
typedef float f32x4 __attribute__((ext_vector_type(4)));

__device__ __forceinline__ unsigned short f2bf(float f) {
  return __builtin_bit_cast(unsigned short, (__bf16)f);
}

// async global->LDS, 16B per lane. lds dst = uniform base + lane*16.
__device__ __forceinline__ void gl2lds16(const unsigned short* g,
                                         unsigned short* l) {
  __builtin_amdgcn_global_load_lds(
      (const __attribute__((address_space(1))) unsigned int*)(const void*)g,
      (__attribute__((address_space(3))) unsigned int*)(void*)l, 16, 0, 0);
}

// ---------------- kernel 1: router ----------------
__global__ __launch_bounds__(64) void router_k(
    const float* __restrict__ x, const float* __restrict__ wg,
    int* __restrict__ topi, float* __restrict__ topw) {
  int t = blockIdx.x;
  int lane = threadIdx.x;
  const float* hx = x + (size_t)t * DMODEL;
  float acc[NEXP];
#pragma unroll
  for (int e = 0; e < NEXP; ++e) acc[e] = 0.f;
  for (int i = lane; i < DMODEL; i += 64) {
    float xi = hx[i];
    const float* w = wg + (size_t)i * NEXP;
#pragma unroll
    for (int e = 0; e < NEXP; ++e) acc[e] += xi * w[e];
  }
#pragma unroll
  for (int off = 32; off > 0; off >>= 1) {
#pragma unroll
    for (int e = 0; e < NEXP; ++e) acc[e] += __shfl_down(acc[e], off);
  }
  if (lane == 0) {
    float m = acc[0];
#pragma unroll
    for (int e = 1; e < NEXP; ++e) m = fmaxf(m, acc[e]);
    float p[NEXP], s = 0.f;
#pragma unroll
    for (int e = 0; e < NEXP; ++e) { p[e] = expf(acc[e] - m); s += p[e]; }
    float inv = 1.f / s;
#pragma unroll
    for (int e = 0; e < NEXP; ++e) p[e] *= inv;
    int i1 = 0;
#pragma unroll
    for (int e = 1; e < NEXP; ++e) if (p[e] > p[i1]) i1 = e;
    int i2 = (i1 == 0) ? 1 : 0;
#pragma unroll
    for (int e = 0; e < NEXP; ++e) if (e != i1 && p[e] > p[i2]) i2 = e;
    float w1 = p[i1], w2 = p[i2];
    float rs = 1.f / (w1 + w2);
    topi[2 * t] = i1;
    topi[2 * t + 1] = i2;
    topw[2 * t] = w1 * rs;
    topw[2 * t + 1] = w2 * rs;
  }
}

// ---------------- kernel 2: per-expert compaction ----------------
__global__ __launch_bounds__(512) void compact_k(
    const int* __restrict__ topi, const float* __restrict__ topw,
    int* __restrict__ offsets, int* __restrict__ perm,
    float* __restrict__ wrow) {
  int tid = threadIdx.x;
  int w = tid >> 6, lane = tid & 63;
  __shared__ int hist[NEXP][NEXP];
  __shared__ int base_s[NEXP][NEXP];
  unsigned long long ltmask = (1ULL << lane) - 1ULL;

  int c[NEXP];
#pragma unroll
  for (int ex = 0; ex < NEXP; ++ex) c[ex] = 0;
  for (int it = 0; it < 8; ++it) {
    int j = w * 512 + it * 64 + lane;
    int e = topi[j];
#pragma unroll
    for (int ex = 0; ex < NEXP; ++ex) {
      unsigned long long m = __ballot(e == ex);
      c[ex] += __popcll(m);
    }
  }
  if (lane == 0) {
#pragma unroll
    for (int ex = 0; ex < NEXP; ++ex) hist[w][ex] = c[ex];
  }
  __syncthreads();
  if (tid == 0) {
    int s = 0;
    for (int ex = 0; ex < NEXP; ++ex) {
      offsets[ex] = s;
      int t = s;
      for (int w2 = 0; w2 < NEXP; ++w2) { base_s[w2][ex] = t; t += hist[w2][ex]; }
      s = t;
    }
    offsets[NEXP] = s;
  }
  __syncthreads();
  int rb[NEXP];
#pragma unroll
  for (int ex = 0; ex < NEXP; ++ex) rb[ex] = base_s[w][ex];
  for (int it = 0; it < 8; ++it) {
    int j = w * 512 + it * 64 + lane;
    int e = topi[j];
    float pw = topw[j];
#pragma unroll
    for (int ex = 0; ex < NEXP; ++ex) {
      unsigned long long m = __ballot(e == ex);
      if (e == ex) {
        int p = rb[ex] + __popcll(m & ltmask);
        perm[p] = j >> 1;
        wrow[p] = pw;
      }
      rb[ex] += __popcll(m);
    }
  }
}

// ---------------- pre-pass: gather x rows -> bf16 Abf ----------------
__global__ __launch_bounds__(256) void gather_x_k(
    const float* __restrict__ x, const int* __restrict__ perm,
    unsigned short* __restrict__ abf) {
  int p = blockIdx.x;
  int src = perm[p];
  int c = threadIdx.x * 4;
  float4 v = *(const float4*)(x + (size_t)src * DMODEL + c);
  ushort4 u;
  u.x = f2bf(v.x); u.y = f2bf(v.y); u.z = f2bf(v.z); u.w = f2bf(v.w);
  *(ushort4*)(&abf[(size_t)p * DMODEL + c]) = u;
}

// ---------------- pre-pass: transpose+convert weights ----------------
// src [E][K][N] fp32 -> dst [E][N][K] bf16. grid (N/64, K/64, E).
#define TP 68
__global__ __launch_bounds__(256) void transw_k(
    const float* __restrict__ src, unsigned short* __restrict__ dst,
    int K, int N) {
  __shared__ __align__(16) unsigned short sm[64 * TP];
  int e = blockIdx.z;
  int kt = blockIdx.y * 64, nt = blockIdx.x * 64;
  const float* s = src + (size_t)e * K * N;
  unsigned short* d = dst + (size_t)e * N * K;
  int tid = threadIdx.x;
  int r0 = tid >> 4, c0 = (tid & 15) * 4;
#pragma unroll
  for (int rr = 0; rr < 4; ++rr) {
    int k = r0 + rr * 16;
    float4 v = *(const float4*)(s + (size_t)(kt + k) * N + nt + c0);
    ushort4 u;
    u.x = f2bf(v.x); u.y = f2bf(v.y); u.z = f2bf(v.z); u.w = f2bf(v.w);
    *(ushort4*)(&sm[k * TP + c0]) = u;
  }
  __syncthreads();
#pragma unroll
  for (int rr = 0; rr < 4; ++rr) {
    int n = r0 + rr * 16;
    ushort4 u;
    u.x = sm[(c0 + 0) * TP + n];
    u.y = sm[(c0 + 1) * TP + n];
    u.z = sm[(c0 + 2) * TP + n];
    u.w = sm[(c0 + 3) * TP + n];
    *(ushort4*)(&d[(size_t)(nt + n) * K + kt + c0]) = u;
  }
}

// ---------------- kernel 3: fused gate/in GEMM + silu (m97-style) --------
// A: Abf [4096][1024] bf16. B: Wgt/Wit [E][4096 n][1024 k] bf16.
// Tile 128x64, BK=32, 4 waves 2x2 (each 64x32, dual matrices).
__global__ __launch_bounds__(256) void hid_k(
    const unsigned short* __restrict__ abf,
    const unsigned short* __restrict__ wgt,
    const unsigned short* __restrict__ wit,
    const int* __restrict__ offsets, const float* __restrict__ wrow,
    unsigned short* __restrict__ hid) {
  int e = blockIdx.z;
  int off = offsets[e], cnt = offsets[e + 1] - off;
  int nb = blockIdx.x * 64;
  const unsigned short* wge = wgt + (size_t)e * DMLP * DMODEL;
  const unsigned short* wie = wit + (size_t)e * DMLP * DMODEL;

  __shared__ __align__(16) unsigned short As[128 * 32];
  __shared__ __align__(16) unsigned short Bg[64 * 32];
  __shared__ __align__(16) unsigned short Bi[64 * 32];

  int tid = threadIdx.x;
  int lane = tid & 63, wid = tid >> 6;
  int wm = (wid & 1) * 64, wn = (wid >> 1) * 32;
  int lr = lane & 15, q = lane >> 4;
  int sr = lane >> 2, ko = lane & 3;  // staging: sub-row, k-octet

  // B staging sources (constant over m0)
  const unsigned short* gSrc =
      wge + (size_t)(nb + wid * 16 + sr) * DMODEL + ko * 8;
  const unsigned short* iSrc =
      wie + (size_t)(nb + wid * 16 + sr) * DMODEL + ko * 8;
  unsigned short* ldsA0 = As + wid * 1024;
  unsigned short* ldsA1 = As + wid * 1024 + 512;
  unsigned short* ldsBg = Bg + wid * 512;
  unsigned short* ldsBi = Bi + wid * 512;

  for (int m0 = blockIdx.y * 128; m0 < cnt; m0 += YB * 128) {
    int ra = off + m0 + wid * 32 + sr;
    int rb = ra + 16;
    ra = ra < (TOTROW - 1) ? ra : (TOTROW - 1);
    rb = rb < (TOTROW - 1) ? rb : (TOTROW - 1);
    const unsigned short* aSrc0 = abf + (size_t)ra * DMODEL + ko * 8;
    const unsigned short* aSrc1 = abf + (size_t)rb * DMODEL + ko * 8;

    f32x4 accg[4][2], acci[4][2];
    f32x4 z = {0.f, 0.f, 0.f, 0.f};
#pragma unroll
    for (int i = 0; i < 4; ++i)
#pragma unroll
      for (int j = 0; j < 2; ++j) { accg[i][j] = z; acci[i][j] = z; }

    for (int k0 = 0; k0 < DMODEL; k0 += 32) {
      gl2lds16(aSrc0 + k0, ldsA0);
      gl2lds16(aSrc1 + k0, ldsA1);
      gl2lds16(gSrc + k0, ldsBg);
      gl2lds16(iSrc + k0, ldsBi);
      __syncthreads();
      bf16x8 af[4], bgf[2], bif[2];
#pragma unroll
      for (int i = 0; i < 4; ++i)
        af[i] = *(const bf16x8*)(&As[(wm + i * 16 + lr) * 32 + q * 8]);
#pragma unroll
      for (int j = 0; j < 2; ++j) {
        bgf[j] = *(const bf16x8*)(&Bg[(wn + j * 16 + lr) * 32 + q * 8]);
        bif[j] = *(const bf16x8*)(&Bi[(wn + j * 16 + lr) * 32 + q * 8]);
      }
#pragma unroll
      for (int i = 0; i < 4; ++i)
#pragma unroll
        for (int j = 0; j < 2; ++j) {
          accg[i][j] = __builtin_amdgcn_mfma_f32_16x16x32_bf16(
              af[i], bgf[j], accg[i][j], 0, 0, 0);
          acci[i][j] = __builtin_amdgcn_mfma_f32_16x16x32_bf16(
              af[i], bif[j], acci[i][j], 0, 0, 0);
        }
      __syncthreads();
    }
    // epilogue: silu(g)*v*wrow -> bf16
#pragma unroll
    for (int i = 0; i < 4; ++i)
#pragma unroll
      for (int j = 0; j < 2; ++j)
#pragma unroll
        for (int r = 0; r < 4; ++r) {
          int row = wm + i * 16 + q * 4 + r;
          int pl = m0 + row;
          if (pl < cnt) {
            int pos = off + pl;
            float g = accg[i][j][r], vv = acci[i][j][r];
            float hv = (g / (1.f + expf(-g))) * vv * wrow[pos];
            hid[(size_t)pos * DMLP + nb + wn + j * 16 + lr] = f2bf(hv);
          }
        }
  }
}

// ---------------- kernel 4: out GEMM (m97-style), atomic accumulate ------
// A: hid [4096][4096] bf16. B: Wot [E][1024 n][4096 k] bf16.
__global__ __launch_bounds__(256) void out_k(
    const unsigned short* __restrict__ hid,
    const unsigned short* __restrict__ wot,
    const int* __restrict__ offsets, const int* __restrict__ perm,
    float* __restrict__ out) {
  int e = blockIdx.z;
  int off = offsets[e], cnt = offsets[e + 1] - off;
  int nb = blockIdx.x * 64;
  const unsigned short* woe = wot + (size_t)e * DMLP * DMODEL;

  __shared__ __align__(16) unsigned short As[128 * 32];
  __shared__ __align__(16) unsigned short Bs[64 * 32];

  int tid = threadIdx.x;
  int lane = tid & 63, wid = tid >> 6;
  int wm = (wid & 1) * 64, wn = (wid >> 1) * 32;
  int lr = lane & 15, q = lane >> 4;
  int sr = lane >> 2, ko = lane & 3;

  const unsigned short* bSrc =
      woe + (size_t)(nb + wid * 16 + sr) * DMLP + ko * 8;
  unsigned short* ldsA0 = As + wid * 1024;
  unsigned short* ldsA1 = As + wid * 1024 + 512;
  unsigned short* ldsB = Bs + wid * 512;

  for (int m0 = blockIdx.y * 128; m0 < cnt; m0 += YB * 128) {
    int ra = off + m0 + wid * 32 + sr;
    int rb = ra + 16;
    ra = ra < (TOTROW - 1) ? ra : (TOTROW - 1);
    rb = rb < (TOTROW - 1) ? rb : (TOTROW - 1);
    const unsigned short* aSrc0 = hid + (size_t)ra * DMLP + ko * 8;
    const unsigned short* aSrc1 = hid + (size_t)rb * DMLP + ko * 8;

    f32x4 acc[4][2];
    f32x4 z = {0.f, 0.f, 0.f, 0.f};
#pragma unroll
    for (int i = 0; i < 4; ++i)
#pragma unroll
      for (int j = 0; j < 2; ++j) acc[i][j] = z;

    for (int kk = 0; kk < DMLP; kk += 32) {
      gl2lds16(aSrc0 + kk, ldsA0);
      gl2lds16(aSrc1 + kk, ldsA1);
      gl2lds16(bSrc + kk, ldsB);
      __syncthreads();
      bf16x8 af[4], bfr[2];
#pragma unroll
      for (int i = 0; i < 4; ++i)
        af[i] = *(const bf16x8*)(&As[(wm + i * 16 + lr) * 32 + q * 8]);
#pragma unroll
      for (int j = 0; j < 2; ++j)
        bfr[j] = *(const bf16x8*)(&Bs[(wn + j * 16 + lr) * 32 + q * 8]);
#pragma unroll
      for (int i = 0; i < 4; ++i)
#pragma unroll
        for (int j = 0; j < 2; ++j)
          acc[i][j] = __builtin_amdgcn_mfma_f32_16x16x32_bf16(
              af[i], bfr[j], acc[i][j], 0, 0, 0);
      __syncthreads();
    }
#pragma unroll
    for (int i = 0; i < 4; ++i)
#pragma unroll
      for (int j = 0; j < 2; ++j)
#pragma unroll
        for (int r = 0; r < 4; ++r) {
          int row = wm + i * 16 + q * 4 + r;
          int pl = m0 + row;
          if (pl < cnt) {
            int tok = perm[off + pl];
            atomicAdd(&out[(size_t)tok * DMODEL + nb + wn + j * 16 + lr],
                      acc[i][j][r]);
          }
        }
  }
}

// ================= fallback (R1) path, used if ws too small ===============
#define BPITCH 40
__global__ __launch_bounds__(256) void hid_fb(
    const float* __restrict__ x, const float* __restrict__ weg,
    const float* __restrict__ wei, const int* __restrict__ offsets,
    const int* __restrict__ perm, const float* __restrict__ wrow,
    unsigned short* __restrict__ hid) {
  int e = blockIdx.z;
  int off = offsets[e], end = offsets[e + 1];
  int cnt = end - off;
  int m0 = blockIdx.y * 128;
  if (m0 >= cnt) return;
  int nb = blockIdx.x * 64;
  const float* wg = weg + (size_t)e * DMODEL * DMLP;
  const float* wi = wei + (size_t)e * DMODEL * DMLP;
  __shared__ unsigned short As[128 * BPITCH];
  __shared__ unsigned short Bg[64 * BPITCH];
  __shared__ unsigned short Bi[64 * BPITCH];
  int tid = threadIdx.x;
  int lane = tid & 63, wid = tid >> 6;
  int wm = (wid & 1) * 64, wn = (wid >> 1) * 32;
  int lr = lane & 15, q = lane >> 4;
  f32x4 accg[4][2], acci[4][2];
  f32x4 z = {0.f, 0.f, 0.f, 0.f};
#pragma unroll
  for (int i = 0; i < 4; ++i)
#pragma unroll
    for (int j = 0; j < 2; ++j) { accg[i][j] = z; acci[i][j] = z; }
  const float* aptr[4];
  int adst[4];
#pragma unroll
  for (int it = 0; it < 4; ++it) {
    int task = tid + it * 256;
    int r = task >> 3, kc = (task & 7) * 4;
    int pl = m0 + r;
    int src = perm[off + ((pl < cnt) ? pl : 0)];
    aptr[it] = x + (size_t)src * DMODEL + kc;
    adst[it] = r * BPITCH + kc;
  }
  int tn = (tid & 15) * 4, tk = (tid >> 4) * 2;
  for (int k0 = 0; k0 < DMODEL; k0 += 32) {
#pragma unroll
    for (int it = 0; it < 4; ++it) {
      float4 v = *(const float4*)(aptr[it] + k0);
      ushort4 u;
      u.x = f2bf(v.x); u.y = f2bf(v.y); u.z = f2bf(v.z); u.w = f2bf(v.w);
      *(ushort4*)(&As[adst[it]]) = u;
    }
    {
      const float* pg = wg + (size_t)(k0 + tk) * DMLP + nb + tn;
      float4 g0 = *(const float4*)(pg);
      float4 g1 = *(const float4*)(pg + DMLP);
      const float* pi = wi + (size_t)(k0 + tk) * DMLP + nb + tn;
      float4 i0 = *(const float4*)(pi);
      float4 i1 = *(const float4*)(pi + DMLP);
      const float* c0 = (const float*)&g0;
      const float* c1 = (const float*)&g1;
      const float* d0 = (const float*)&i0;
      const float* d1 = (const float*)&i1;
#pragma unroll
      for (int cix = 0; cix < 4; ++cix) {
        ushort2 vg; vg.x = f2bf(c0[cix]); vg.y = f2bf(c1[cix]);
        *(ushort2*)(&Bg[(tn + cix) * BPITCH + tk]) = vg;
        ushort2 vi; vi.x = f2bf(d0[cix]); vi.y = f2bf(d1[cix]);
        *(ushort2*)(&Bi[(tn + cix) * BPITCH + tk]) = vi;
      }
    }
    __syncthreads();
    bf16x8 af[4], bgf[2], bif[2];
#pragma unroll
    for (int i = 0; i < 4; ++i)
      af[i] = *(const bf16x8*)(&As[(wm + i * 16 + lr) * BPITCH + q * 8]);
#pragma unroll
    for (int j = 0; j < 2; ++j) {
      bgf[j] = *(const bf16x8*)(&Bg[(wn + j * 16 + lr) * BPITCH + q * 8]);
      bif[j] = *(const bf16x8*)(&Bi[(wn + j * 16 + lr) * BPITCH + q * 8]);
    }
#pragma unroll
    for (int i = 0; i < 4; ++i)
#pragma unroll
      for (int j = 0; j < 2; ++j) {
        accg[i][j] = __builtin_amdgcn_mfma_f32_16x16x32_bf16(af[i], bgf[j], accg[i][j], 0, 0, 0);
        acci[i][j] = __builtin_amdgcn_mfma_f32_16x16x32_bf16(af[i], bif[j], acci[i][j], 0, 0, 0);
      }
    __syncthreads();
  }
#pragma unroll
  for (int i = 0; i < 4; ++i)
#pragma unroll
    for (int j = 0; j < 2; ++j)
#pragma unroll
      for (int r = 0; r < 4; ++r) {
        int row = wm + i * 16 + q * 4 + r;
        int pl = m0 + row;
        if (pl < cnt) {
          int pos = off + pl;
          float g = accg[i][j][r], vv = acci[i][j][r];
          float hv = (g / (1.f + expf(-g))) * vv * wrow[pos];
          hid[(size_t)pos * DMLP + nb + wn + j * 16 + lr] = f2bf(hv);
        }
      }
}

__global__ __launch_bounds__(256) void out_fb(
    const unsigned short* __restrict__ hid, const float* __restrict__ weo,
    const int* __restrict__ offsets, const int* __restrict__ perm,
    float* __restrict__ out) {
  int e = blockIdx.z;
  int off = offsets[e], end = offsets[e + 1];
  int cnt = end - off;
  int m0 = blockIdx.y * 128;
  if (m0 >= cnt) return;
  int nb = blockIdx.x * 64;
  const float* wo = weo + (size_t)e * DMLP * DMODEL;
  __shared__ unsigned short As[128 * BPITCH];
  __shared__ unsigned short Bs[64 * BPITCH];
  int tid = threadIdx.x;
  int lane = tid & 63, wid = tid >> 6;
  int wm = (wid & 1) * 64, wn = (wid >> 1) * 32;
  int lr = lane & 15, q = lane >> 4;
  f32x4 acc[4][2];
  f32x4 z = {0.f, 0.f, 0.f, 0.f};
#pragma unroll
  for (int i = 0; i < 4; ++i)
#pragma unroll
    for (int j = 0; j < 2; ++j) acc[i][j] = z;
  const unsigned short* aptr[2];
  int adst[2];
#pragma unroll
  for (int it = 0; it < 2; ++it) {
    int task = tid + it * 256;
    int r = task >> 2, kg = (task & 3) * 8;
    int pl = m0 + r;
    int src = off + ((pl < cnt) ? pl : 0);
    aptr[it] = hid + (size_t)src * DMLP + kg;
    adst[it] = r * BPITCH + kg;
  }
  int tn = (tid & 15) * 4, tk = (tid >> 4) * 2;
  for (int k0 = 0; k0 < DMLP; k0 += 32) {
#pragma unroll
    for (int it = 0; it < 2; ++it) {
      uint4 v = *(const uint4*)(aptr[it] + k0);
      *(uint4*)(&As[adst[it]]) = v;
    }
    {
      const float* pb = wo + (size_t)(k0 + tk) * DMODEL + nb + tn;
      float4 b0 = *(const float4*)(pb);
      float4 b1 = *(const float4*)(pb + DMODEL);
      const float* c0 = (const float*)&b0;
      const float* c1 = (const float*)&b1;
#pragma unroll
      for (int cix = 0; cix < 4; ++cix) {
        ushort2 vb; vb.x = f2bf(c0[cix]); vb.y = f2bf(c1[cix]);
        *(ushort2*)(&Bs[(tn + cix) * BPITCH + tk]) = vb;
      }
    }
    __syncthreads();
    bf16x8 af[4], bfr[2];
#pragma unroll
    for (int i = 0; i < 4; ++i)
      af[i] = *(const bf16x8*)(&As[(wm + i * 16 + lr) * BPITCH + q * 8]);
#pragma unroll
    for (int j = 0; j < 2; ++j)
      bfr[j] = *(const bf16x8*)(&Bs[(wn + j * 16 + lr) * BPITCH + q * 8]);
#pragma unroll
    for (int i = 0; i < 4; ++i)
#pragma unroll
      for (int j = 0; j < 2; ++j)
        acc[i][j] = __builtin_amdgcn_mfma_f32_16x16x32_bf16(af[i], bfr[j], acc[i][j], 0, 0, 0);
    __syncthreads();
  }
#pragma unroll
  for (int i = 0; i < 4; ++i)
#pragma unroll
    for (int j = 0; j < 2; ++j)
#pragma unroll
      for (int r = 0; r < 4; ++r) {
        int row = wm + i * 16 + q * 4 + r;
        int pl = m0 + row;
        if (pl < cnt) {
          int tok = perm[off + pl];
          atomicAdd(&out[(size_t)tok * DMODEL + nb + wn + j * 16 + lr],
                    acc[i][j][r]);
        }
      }
}

// ---------------- launcher ----------------
extern "C" void kernel_launch(void* const* d_in, const int* in_sizes, int n_in,
                              void* d_out, int out_size, void* d_ws,
                              size_t ws_size, hipStream_t stream) {
  const float* x = (const float*)d_in[0];
  const float* wgate = (const float*)d_in[1];
  const float* weg = (const float*)d_in[2];
  const float* wei = (const float*)d_in[3];
  const float* weo = (const float*)d_in[4];
  float* out = (float*)d_out;

  char* ws = (char*)d_ws;
  int* topi = (int*)(ws + 0);                  // 16 KB
  float* topw = (float*)(ws + (16 << 10));     // 16 KB
  int* offsets = (int*)(ws + (32 << 10));      // 64 B
  int* perm = (int*)(ws + (33 << 10));         // 16 KB
  float* wrow = (float*)(ws + (49 << 10));     // 16 KB
  const size_t MB = 1ull << 20;
  unsigned short* abf = (unsigned short*)(ws + 128 * 1024);      // 8 MB
  unsigned short* hid = (unsigned short*)(ws + 8 * MB + 128 * 1024);   // 32 MB
  unsigned short* wgt = (unsigned short*)(ws + 40 * MB + 128 * 1024);  // 64 MB
  unsigned short* wit = (unsigned short*)(ws + 104 * MB + 128 * 1024); // 64 MB
  unsigned short* wot = wgt;  // reuse Wgt region after hid_k completes
  const size_t need = 168 * MB + 128 * 1024;

  hipMemsetAsync(d_out, 0, (size_t)out_size * sizeof(float), stream);
  router_k<<<dim3(T_TOK), dim3(64), 0, stream>>>(x, wgate, topi, topw);
  compact_k<<<dim3(1), dim3(512), 0, stream>>>(topi, topw, offsets, perm, wrow);

  if (ws_size >= need) {
    gather_x_k<<<dim3(TOTROW), dim3(256), 0, stream>>>(x, perm, abf);
    transw_k<<<dim3(DMLP / 64, DMODEL / 64, NEXP), dim3(256), 0, stream>>>(
        weg, wgt, DMODEL, DMLP);
    transw_k<<<dim3(DMLP / 64, DMODEL / 64, NEXP), dim3(256), 0, stream>>>(
        wei, wit, DMODEL, DMLP);
    hid_k<<<dim3(DMLP / 64, YB, NEXP), dim3(256), 0, stream>>>(
        abf, wgt, wit, offsets, wrow, hid);
    transw_k<<<dim3(DMODEL / 64, DMLP / 64, NEXP), dim3(256), 0, stream>>>(
        weo, wot, DMLP, DMODEL);
    out_k<<<dim3(DMODEL / 64, YB, NEXP), dim3(256), 0, stream>>>(
        hid, wot, offsets, perm, out);
  } else {
    unsigned short* hid_s = (unsigned short*)(ws + (65 << 10));
    hid_fb<<<dim3(DMLP / 64, T_TOK / 128, NEXP), dim3(256), 0, stream>>>(
        x, weg, wei, offsets, perm, wrow, hid_s);
    out_fb<<<dim3(DMODEL / 64, T_TOK / 128, NEXP), dim3(256), 0, stream>>>(
        hid_s, weo, offsets, perm, out);
  }
}